// Round 11
// baseline (219.486 us; speedup 1.0000x reference)
//
#include <hip/hip_runtime.h>
#include <hip/hip_bf16.h>
#include <math.h>

#define NN 100000
#define DD 384
#define HH 128
#define KK 5

typedef __attribute__((ext_vector_type(8))) short short8;
typedef __attribute__((ext_vector_type(4))) float f32x4;

constexpr float INIT_VAL = 1.4142135623730951e-3f; // 1/sqrt(N*K)
constexpr float RSQRT5   = 0.44721359549995793f;   // 1/sqrt(5)

// split f32 -> bf16 hi + bf16 lo (truncation; |x - hi - lo| <= 2^-16 |x|)
__device__ __forceinline__ void split_bf16(float x, ushort& hi, ushort& lo) {
    unsigned xb = __float_as_uint(x);
    hi = (ushort)(xb >> 16);
    float hif = __uint_as_float(((unsigned)hi) << 16);
    lo = (ushort)(__float_as_uint(x - hif) >> 16);
}

// split 8 floats (two float4, k-consecutive) into hi/lo bf16 short8 fragments
__device__ __forceinline__ void split8(float4 x, float4 y, short8& h, short8& l) {
    union { short8 s; unsigned u[4]; } H, L;
    float f[8] = {x.x, x.y, x.z, x.w, y.x, y.y, y.z, y.w};
#pragma unroll
    for (int d = 0; d < 4; ++d) {
        unsigned b0 = __float_as_uint(f[2 * d]);
        unsigned b1 = __float_as_uint(f[2 * d + 1]);
        H.u[d] = (b0 >> 16) | (b1 & 0xFFFF0000u);
        float l0 = f[2 * d]     - __uint_as_float(b0 & 0xFFFF0000u);
        float l1 = f[2 * d + 1] - __uint_as_float(b1 & 0xFFFF0000u);
        L.u[d] = (__float_as_uint(l0) >> 16) | (__float_as_uint(l1) & 0xFFFF0000u);
    }
    h = H.s;
    l = L.s;
}

// ---------------- fused prep ----------------
// block 0: parallel fold qv @ W1[384:768] into bias; zero ssp
// blocks 1..48: pack W1[0:384] into fragment layout [ks(12)][frag(16=nt*2+hl)][lane(64)][e(8)]
// blocks 49..: transpose nbr to SoA + zero the three scatter buffers
__global__ __launch_bounds__(256) void prep_kernel(
    const float* __restrict__ qv, const float* __restrict__ W1,
    const float* __restrict__ b1, const int* __restrict__ nbr,
    float* __restrict__ b1p, ushort* __restrict__ W1p,
    int* __restrict__ nbrT, float* __restrict__ sA, float* __restrict__ sB,
    float* __restrict__ sC, float* __restrict__ ssp) {
    const int b = blockIdx.x, tid = threadIdx.x;
    if (b == 0) {
        __shared__ float part[256];
        const int h = tid & 127, half = tid >> 7;
        float s = 0.f;
        const float* Wq = W1 + (size_t)(DD + half * 192) * HH + h;
        const float* qh = qv + half * 192;
#pragma unroll 8
        for (int k = 0; k < 192; ++k)
            s = fmaf(qh[k], Wq[(size_t)k * HH], s);
        part[tid] = s;
        __syncthreads();
        if (tid < HH) b1p[tid] = part[tid] + part[tid + 128] + b1[tid];
        if (tid == 0) ssp[0] = 0.f;
    } else if (b <= 48) {
        int t = (b - 1) * 256 + tid;       // t < 12288 = 12ks x 16frag x 64lane
        int lane = t & 63;
        int q = t >> 6;                    // 0..191
        int frag = q & 15;
        int ks = q >> 4;                   // 0..11
        int nt = frag >> 1, hl = frag & 1;
        int col = nt * 16 + (lane & 15);
        int k0 = ks * 32 + ((lane >> 4) << 3);
#pragma unroll
        for (int e = 0; e < 8; ++e) {
            ushort hv, lv;
            split_bf16(W1[(size_t)(k0 + e) * HH + col], hv, lv);
            W1p[(size_t)t * 8 + e] = hl ? lv : hv;
        }
    } else {
        int i = (b - 49) * 256 + tid;
        if (i < NN) {
#pragma unroll
            for (int j = 0; j < KK; ++j) {
                nbrT[j * NN + i] = nbr[i * KK + j];
                sA[j * NN + i] = 0.f;
                sB[j * NN + i] = 0.f;
                sC[j * NN + i] = 0.f;
            }
        }
    }
}

// ---------------- wave-independent asm-pipelined MFMA MLP ----------------
// Wave = 32 rows x 128 cols. No LDS, no barriers, no compiler loads in main loop.
// A: depth-3 ks rotation (12 float4 pinned), direct per-lane global loads.
// B: depth-1 ks rotation (32 float4 pinned) from L2 (pre-packed fragments).
// Counted vmcnt (24/20/0), never drained mid-loop. Epilogue in-wave + fused walk1.
__global__ __launch_bounds__(256) void mlp_mfma_kernel(
    const float* __restrict__ emb, const ushort* __restrict__ W1p,
    const float* __restrict__ b1p, const float* __restrict__ W2,
    const float* __restrict__ b2, const int* __restrict__ nbrT,
    float* __restrict__ gout /* [KK][NN] */, float* __restrict__ sA) {
    const int tid = threadIdx.x;
    const int lane = tid & 63;
    const int wid = tid >> 6;
    const int rowBase = (blockIdx.x * 4 + wid) * 32;
    const int gp = lane >> 4;     // 0..3 (k-subblock / row-group)
    const int cl = lane & 15;     // col-in-tile / row-in-tile

    int r0 = min(rowBase + cl, NN - 1);
    int r1 = min(rowBase + 16 + cl, NN - 1);
    const float* aRow0 = emb + (size_t)r0 * DD + (gp << 3);
    const float* aRow1 = emb + (size_t)r1 * DD + (gp << 3);
    const char* bBase = (const char*)W1p + lane * 16;

    float4 aR[3][2][2];   // [ks%3][mt][chunk]
    float4 bR[2][16];     // [ks&1][frag]
    f32x4  acc[2][8];     // [mt][nt]
#pragma unroll
    for (int mt = 0; mt < 2; ++mt)
#pragma unroll
        for (int nt = 0; nt < 8; ++nt) acc[mt][nt] = (f32x4){0.f, 0.f, 0.f, 0.f};

#define ISSUE_A(S, KS) {                                                              \
    const float* p0_ = aRow0 + (KS) * 32;                                             \
    const float* p1_ = aRow1 + (KS) * 32;                                             \
    asm volatile("global_load_dwordx4 %0, %1, off"           : "=v"(aR[S][0][0]) : "v"(p0_)); \
    asm volatile("global_load_dwordx4 %0, %1, off offset:16" : "=v"(aR[S][0][1]) : "v"(p0_)); \
    asm volatile("global_load_dwordx4 %0, %1, off"           : "=v"(aR[S][1][0]) : "v"(p1_)); \
    asm volatile("global_load_dwordx4 %0, %1, off offset:16" : "=v"(aR[S][1][1]) : "v"(p1_)); }

#define ISSUE_B(S, KS) {                                                              \
    _Pragma("unroll")                                                                 \
    for (int g_ = 0; g_ < 4; ++g_) {                                                  \
        const char* pg_ = bBase + (KS) * 16384 + g_ * 4096;                           \
        asm volatile("global_load_dwordx4 %0, %1, off"             : "=v"(bR[S][g_ * 4 + 0]) : "v"(pg_)); \
        asm volatile("global_load_dwordx4 %0, %1, off offset:1024" : "=v"(bR[S][g_ * 4 + 1]) : "v"(pg_)); \
        asm volatile("global_load_dwordx4 %0, %1, off offset:2048" : "=v"(bR[S][g_ * 4 + 2]) : "v"(pg_)); \
        asm volatile("global_load_dwordx4 %0, %1, off offset:3072" : "=v"(bR[S][g_ * 4 + 3]) : "v"(pg_)); } }

#define COMPUTE(AS, BS) {                                                             \
    short8 ah0, al0, ah1, al1;                                                        \
    split8(aR[AS][0][0], aR[AS][0][1], ah0, al0);                                     \
    split8(aR[AS][1][0], aR[AS][1][1], ah1, al1);                                     \
    _Pragma("unroll")                                                                 \
    for (int nt = 0; nt < 8; ++nt) {                                                  \
        short8 bh = __builtin_bit_cast(short8, bR[BS][nt * 2]);                       \
        short8 bl = __builtin_bit_cast(short8, bR[BS][nt * 2 + 1]);                   \
        acc[0][nt] = __builtin_amdgcn_mfma_f32_16x16x32_bf16(ah0, bh, acc[0][nt], 0, 0, 0); \
        acc[1][nt] = __builtin_amdgcn_mfma_f32_16x16x32_bf16(ah1, bh, acc[1][nt], 0, 0, 0); \
        acc[0][nt] = __builtin_amdgcn_mfma_f32_16x16x32_bf16(al0, bh, acc[0][nt], 0, 0, 0); \
        acc[1][nt] = __builtin_amdgcn_mfma_f32_16x16x32_bf16(al1, bh, acc[1][nt], 0, 0, 0); \
        acc[0][nt] = __builtin_amdgcn_mfma_f32_16x16x32_bf16(ah0, bl, acc[0][nt], 0, 0, 0); \
        acc[1][nt] = __builtin_amdgcn_mfma_f32_16x16x32_bf16(ah1, bl, acc[1][nt], 0, 0, 0); } }

#define WAIT24 { asm volatile("s_waitcnt vmcnt(24)" ::: "memory"); __builtin_amdgcn_sched_barrier(0); }
#define WAIT20 { asm volatile("s_waitcnt vmcnt(20)" ::: "memory"); __builtin_amdgcn_sched_barrier(0); }
#define WAIT0  { asm volatile("s_waitcnt vmcnt(0)"  ::: "memory"); __builtin_amdgcn_sched_barrier(0); }

    // prologue: A0, B0, A1 (FIFO order matters for vmcnt counts)
    ISSUE_A(0, 0)
    ISSUE_B(0, 0)
    ISSUE_A(1, 1)

    // phase k: issue B(k+1), A(k+2); wait; compute slot k
    ISSUE_B(1, 1)   ISSUE_A(2, 2)   WAIT24  COMPUTE(0, 0)   // k=0
    ISSUE_B(0, 2)   ISSUE_A(0, 3)   WAIT24  COMPUTE(1, 1)   // k=1
    ISSUE_B(1, 3)   ISSUE_A(1, 4)   WAIT24  COMPUTE(2, 0)   // k=2
    ISSUE_B(0, 4)   ISSUE_A(2, 5)   WAIT24  COMPUTE(0, 1)   // k=3
    ISSUE_B(1, 5)   ISSUE_A(0, 6)   WAIT24  COMPUTE(1, 0)   // k=4
    ISSUE_B(0, 6)   ISSUE_A(1, 7)   WAIT24  COMPUTE(2, 1)   // k=5
    ISSUE_B(1, 7)   ISSUE_A(2, 8)   WAIT24  COMPUTE(0, 0)   // k=6
    ISSUE_B(0, 8)   ISSUE_A(0, 9)   WAIT24  COMPUTE(1, 1)   // k=7
    ISSUE_B(1, 9)   ISSUE_A(1, 10)  WAIT24  COMPUTE(2, 0)   // k=8
    ISSUE_B(0, 10)  ISSUE_A(2, 11)  WAIT24  COMPUTE(0, 1)   // k=9
    ISSUE_B(1, 11)                  WAIT20  COMPUTE(1, 0)   // k=10
                                    WAIT0   COMPUTE(2, 1)   // k=11

#undef ISSUE_A
#undef ISSUE_B
#undef COMPUTE
#undef WAIT24
#undef WAIT20
#undef WAIT0

    // ---- in-wave epilogue: bias+relu, xW2, 16-lane reduce, g + fused walk1 ----
    float p[2][4][KK];
#pragma unroll
    for (int mt = 0; mt < 2; ++mt)
#pragma unroll
        for (int r = 0; r < 4; ++r)
#pragma unroll
            for (int j = 0; j < KK; ++j) p[mt][r][j] = 0.f;

#pragma unroll
    for (int nt = 0; nt < 8; ++nt) {
        int col = nt * 16 + cl;
        float b1v = b1p[col];
        float w2v[KK];
#pragma unroll
        for (int j = 0; j < KK; ++j) w2v[j] = W2[col * KK + j];
#pragma unroll
        for (int mt = 0; mt < 2; ++mt)
#pragma unroll
            for (int r = 0; r < 4; ++r) {
                float v = fmaxf(acc[mt][nt][r] + b1v, 0.f);
#pragma unroll
                for (int j = 0; j < KK; ++j) p[mt][r][j] = fmaf(v, w2v[j], p[mt][r][j]);
            }
    }
#pragma unroll
    for (int off = 1; off < 16; off <<= 1)
#pragma unroll
        for (int mt = 0; mt < 2; ++mt)
#pragma unroll
            for (int r = 0; r < 4; ++r)
#pragma unroll
                for (int j = 0; j < KK; ++j) p[mt][r][j] += __shfl_xor(p[mt][r][j], off, 64);

    if (cl == 0) {
#pragma unroll
        for (int mt = 0; mt < 2; ++mt)
#pragma unroll
            for (int r = 0; r < 4; ++r) {
                int node = rowBase + mt * 16 + gp * 4 + r;
                if (node < NN) {
                    float a[KK], an2 = 0.f;
#pragma unroll
                    for (int j = 0; j < KK; ++j) {
                        a[j] = p[mt][r][j] + b2[j];
                        an2 = fmaf(a[j], a[j], an2);
                    }
                    float an = sqrtf(an2);
                    bool valid = (an2 > 0.f) && isfinite(an);
                    float g5[KK], ssum = 0.f;
#pragma unroll
                    for (int j = 0; j < KK; ++j) {
                        g5[j] = valid ? (a[j] / an) : RSQRT5;
                        gout[j * NN + node] = g5[j];
                        ssum += g5[j];
                    }
                    float d = ssum * INIT_VAL;   // fused walk step 1 (uniform state)
#pragma unroll
                    for (int j = 0; j < KK; ++j)
                        atomicAdd(&sA[j * NN + nbrT[j * NN + node]], g5[j] * d);
                }
            }
    }
}

// ---------------- walk step: s_p = g (g.u); scatter-add ----------------
__global__ void walk_step_kernel(const float* __restrict__ g, const int* __restrict__ nbrT,
                                 const float* __restrict__ u, float* __restrict__ v) {
    int i = blockIdx.x * blockDim.x + threadIdx.x;
    if (i >= NN) return;
    float gj[KK], d = 0.f;
#pragma unroll
    for (int j = 0; j < KK; ++j) {
        gj[j] = g[j * NN + i];
        d = fmaf(gj[j], u[j * NN + i], d);
    }
#pragma unroll
    for (int j = 0; j < KK; ++j)
        atomicAdd(&v[j * NN + nbrT[j * NN + i]], gj[j] * d);
}

// ---------------- global sum of squares (float4) ----------------
__global__ void norm_reduce_kernel(const float* __restrict__ u, float* __restrict__ ss) {
    int i = blockIdx.x * blockDim.x + threadIdx.x;
    const int total4 = (KK * NN) / 4;  // 125000
    float s = 0.f;
    for (int idx = i; idx < total4; idx += gridDim.x * blockDim.x) {
        float4 x = reinterpret_cast<const float4*>(u)[idx];
        s = fmaf(x.x, x.x, s);
        s = fmaf(x.y, x.y, s);
        s = fmaf(x.z, x.z, s);
        s = fmaf(x.w, x.w, s);
    }
#pragma unroll
    for (int off = 32; off > 0; off >>= 1) s += __shfl_xor(s, off, 64);
    if ((threadIdx.x & 63) == 0) atomicAdd(ss, s);
}

// ---------------- out[i] = sum_j |u[j][i]| / ||u|| ----------------
__global__ void finalize_kernel(const float* __restrict__ u, const float* __restrict__ ss,
                                float* __restrict__ out) {
    int i = blockIdx.x * blockDim.x + threadIdx.x;
    if (i >= NN) return;
    float s = 0.f;
#pragma unroll
    for (int j = 0; j < KK; ++j) s += fabsf(u[j * NN + i]);
    float nrm = sqrtf(*ss);
    out[i] = (nrm > 0.f) ? (s / nrm) : (KK * INIT_VAL);
}

extern "C" void kernel_launch(void* const* d_in, const int* in_sizes, int n_in,
                              void* d_out, int out_size, void* d_ws, size_t ws_size,
                              hipStream_t stream) {
    const float* emb = (const float*)d_in[0];
    const float* qv  = (const float*)d_in[1];
    const float* W1  = (const float*)d_in[2];
    const float* b1  = (const float*)d_in[3];
    const float* W2  = (const float*)d_in[4];
    const float* b2  = (const float*)d_in[5];
    const int*   nbr = (const int*)d_in[6];
    float* out = (float*)d_out;

    char* ws = (char*)d_ws;
    size_t off = 0;
    auto alloc = [&](size_t bytes) {
        char* p = ws + off;
        off += (bytes + 255) & ~(size_t)255;
        return p;
    };
    float*  b1p  = (float*)alloc(HH * sizeof(float));
    ushort* W1p  = (ushort*)alloc((size_t)2 * DD * HH * sizeof(ushort));
    float*  gbuf = (float*)alloc((size_t)KK * NN * sizeof(float));
    int*    nbrT = (int*)  alloc((size_t)KK * NN * sizeof(int));
    float*  sA   = (float*)alloc((size_t)KK * NN * sizeof(float));
    float*  sB   = (float*)alloc((size_t)KK * NN * sizeof(float));
    float*  sC   = (float*)alloc((size_t)KK * NN * sizeof(float));
    float*  ssp  = (float*)alloc(sizeof(float));

    const int nblk = (NN + 255) / 256;   // 391

    prep_kernel<<<49 + nblk, 256, 0, stream>>>(qv, W1, b1, nbr, b1p, W1p,
                                               nbrT, sA, sB, sC, ssp);
    // 782 blocks x 4 waves x 32 rows = 100096 rows; mlp computes g AND walk step 1
    mlp_mfma_kernel<<<782, 256, 0, stream>>>(emb, W1p, b1p, W2, b2,
                                             nbrT, gbuf, sA);

    walk_step_kernel<<<nblk, 256, 0, stream>>>(gbuf, nbrT, sA, sB);
    walk_step_kernel<<<nblk, 256, 0, stream>>>(gbuf, nbrT, sB, sC);

    norm_reduce_kernel<<<512, 256, 0, stream>>>(sC, ssp);
    finalize_kernel<<<nblk, 256, 0, stream>>>(sC, ssp, out);
}

// Round 12
// 156.132 us; speedup vs baseline: 1.4058x; 1.4058x over previous
//
#include <hip/hip_runtime.h>
#include <hip/hip_bf16.h>
#include <math.h>

#define NN 100000
#define DD 384
#define HH 128
#define KK 5

typedef __attribute__((ext_vector_type(8))) short short8;
typedef __attribute__((ext_vector_type(4))) float f32x4;

constexpr float INIT_VAL = 1.4142135623730951e-3f; // 1/sqrt(N*K)
constexpr float RSQRT5   = 0.44721359549995793f;   // 1/sqrt(5)

// f32 -> bf16 round-to-nearest-even
__device__ __forceinline__ ushort bf16rn(float x) {
    unsigned u = __float_as_uint(x);
    return (ushort)((u + 0x7FFFu + ((u >> 16) & 1u)) >> 16);
}

// ---------------- fused prep ----------------
// block 0: parallel fold qv @ W1[384:768] into bias; zero ssp
// blocks 1..24: pack W1[0:384] into B-fragment layout, bf16 RNE
// blocks 25..: transpose nbr to SoA + zero the three scatter buffers
__global__ __launch_bounds__(256) void prep_kernel(
    const float* __restrict__ qv, const float* __restrict__ W1,
    const float* __restrict__ b1, const int* __restrict__ nbr,
    float* __restrict__ b1p, ushort* __restrict__ W1h,
    int* __restrict__ nbrT, float* __restrict__ sA, float* __restrict__ sB,
    float* __restrict__ sC, float* __restrict__ ssp) {
    const int b = blockIdx.x, tid = threadIdx.x;
    if (b == 0) {
        __shared__ float part[256];
        const int h = tid & 127, half = tid >> 7;
        float s = 0.f;
        const float* Wq = W1 + (size_t)(DD + half * 192) * HH + h;
        const float* qh = qv + half * 192;
#pragma unroll 8
        for (int k = 0; k < 192; ++k)
            s = fmaf(qh[k], Wq[(size_t)k * HH], s);
        part[tid] = s;
        __syncthreads();
        if (tid < HH) b1p[tid] = part[tid] + part[tid + 128] + b1[tid];
        if (tid == 0) ssp[0] = 0.f;
    } else if (b <= 24) {
        int t = (b - 1) * 256 + tid;       // t = (c*12 + ks)*64 + lane, t < 6144
        int l = t & 63;
        int ks = (t >> 6) % 12;
        int c = (t >> 6) / 12;             // hidden 16-col block 0..7
        int k0 = ks * 32 + ((l >> 4) << 3);
        int col = c * 16 + (l & 15);
#pragma unroll
        for (int e = 0; e < 8; ++e)
            W1h[(size_t)t * 8 + e] = bf16rn(W1[(size_t)(k0 + e) * HH + col]);
    } else {
        int i = (b - 25) * 256 + tid;
        if (i < NN) {
#pragma unroll
            for (int j = 0; j < KK; ++j) {
                nbrT[j * NN + i] = nbr[i * KK + j];
                sA[j * NN + i] = 0.f;
                sB[j * NN + i] = 0.f;
                sC[j * NN + i] = 0.f;
            }
        }
    }
}

// ---------------- single-bf16 MFMA MLP (R9 staging structure) + fused walk1 ----------------
// 256 thr = 4 waves (2 M-halves x 2 hidden-halves); tile 64 nodes x 128 hidden.
// A staged f32->bf16(RNE) in 16 KB LDS with XOR swizzle; B pre-packed bf16 frags from L2.
// One MFMA per (mt,nt,kt). Epilogue: relu+W2, 16-lane reduce via padded pbuf, g + walk1.
__global__ __launch_bounds__(256, 2) void mlp_mfma_kernel(
    const float* __restrict__ emb, const ushort* __restrict__ W1h,
    const float* __restrict__ b1p, const float* __restrict__ W2,
    const float* __restrict__ b2, const int* __restrict__ nbrT,
    float* __restrict__ gout /* [KK][NN] */, float* __restrict__ sA) {
    __shared__ __align__(16) ushort Ah[64 * 128];  // 16 KB
    __shared__ float pbuf[64][13];                 // stride 13 (coprime 32) ~3.3 KB

    const int tid = threadIdx.x;
    const int lane = tid & 63;
    const int wid = tid >> 6;
    const int wm = wid >> 1;   // M half (32 rows)
    const int wn = wid & 1;    // hidden half (64 cols)
    const int blkBase = blockIdx.x * 64;

    f32x4 acc[2][4];
#pragma unroll
    for (int mt = 0; mt < 2; ++mt)
#pragma unroll
        for (int nt = 0; nt < 4; ++nt) acc[mt][nt] = (f32x4){0.f, 0.f, 0.f, 0.f};

    float4 aregs[8];
    auto issueA = [&](int t) {
#pragma unroll
        for (int i = 0; i < 8; ++i) {
            int idx = tid + i * 256;
            int r = idx >> 5, c = idx & 31;
            int node = min(blkBase + r, NN - 1);
            aregs[i] = *reinterpret_cast<const float4*>(&emb[(size_t)node * DD + t * 128 + c * 4]);
        }
    };
    auto writeLDS = [&]() {
#pragma unroll
        for (int i = 0; i < 8; ++i) {
            int idx = tid + i * 256;
            int r = idx >> 5, c = idx & 31;
            ushort4 hv;
            hv.x = bf16rn(aregs[i].x);
            hv.y = bf16rn(aregs[i].y);
            hv.z = bf16rn(aregs[i].z);
            hv.w = bf16rn(aregs[i].w);
            int byte = (r * 256 + c * 8) ^ ((r & 7) << 4);
            *reinterpret_cast<ushort4*>(reinterpret_cast<char*>(Ah) + byte) = hv;
        }
    };

    issueA(0);
    writeLDS();
    __syncthreads();

#pragma unroll
    for (int t = 0; t < 3; ++t) {
        if (t < 2) issueA(t + 1);  // in flight across the whole compute phase

        short8 bh[2][4], ah[2][2];
        auto loadB = [&](int kt, int s) {
            int ks = t * 4 + kt;
#pragma unroll
            for (int nt = 0; nt < 4; ++nt) {
                size_t off = ((size_t)((wn * 4 + nt) * 12 + ks) * 64 + lane) * 8;
                bh[s][nt] = *reinterpret_cast<const short8*>(&W1h[off]);
            }
        };
        auto loadA = [&](int kt, int s) {
#pragma unroll
            for (int mt = 0; mt < 2; ++mt) {
                int row = wm * 32 + mt * 16 + (lane & 15);
                int byte = (row * 256 + kt * 64 + ((lane >> 4) << 4)) ^ ((row & 7) << 4);
                ah[s][mt] = *reinterpret_cast<const short8*>(reinterpret_cast<const char*>(Ah) + byte);
            }
        };

        loadB(0, 0);
        loadA(0, 0);
#pragma unroll
        for (int kt = 0; kt < 4; ++kt) {
            const int cur = kt & 1, nxt = cur ^ 1;
            if (kt < 3) {
                loadB(kt + 1, nxt);
                loadA(kt + 1, nxt);
            }
#pragma unroll
            for (int mt = 0; mt < 2; ++mt)
#pragma unroll
                for (int nt = 0; nt < 4; ++nt)
                    acc[mt][nt] = __builtin_amdgcn_mfma_f32_16x16x32_bf16(ah[cur][mt], bh[cur][nt], acc[mt][nt], 0, 0, 0);
        }

        if (t < 2) {
            __syncthreads();   // all waves done reading tile t
            writeLDS();        // load wait lands here, hidden by compute above
            __syncthreads();
        }
    }

    // epilogue: v = relu(h + b1p); p[j] = sum_h v * W2[h][j]; reduce over 16 lanes
    float b1v[4], w2v[4][KK];
#pragma unroll
    for (int nt = 0; nt < 4; ++nt) {
        int h = wn * 64 + nt * 16 + (lane & 15);
        b1v[nt] = b1p[h];
#pragma unroll
        for (int j = 0; j < KK; ++j) w2v[nt][j] = W2[h * KK + j];
    }
#pragma unroll
    for (int mt = 0; mt < 2; ++mt) {
        float p[4][KK];
#pragma unroll
        for (int r = 0; r < 4; ++r)
#pragma unroll
            for (int j = 0; j < KK; ++j) p[r][j] = 0.f;
#pragma unroll
        for (int nt = 0; nt < 4; ++nt)
#pragma unroll
            for (int r = 0; r < 4; ++r) {
                float v = fmaxf(acc[mt][nt][r] + b1v[nt], 0.f);
#pragma unroll
                for (int j = 0; j < KK; ++j) p[r][j] = fmaf(v, w2v[nt][j], p[r][j]);
            }
#pragma unroll
        for (int off = 1; off < 16; off <<= 1)
#pragma unroll
            for (int r = 0; r < 4; ++r)
#pragma unroll
                for (int j = 0; j < KK; ++j) p[r][j] += __shfl_xor(p[r][j], off, 64);
        if ((lane & 15) == 0) {
            int rowbase = wm * 32 + mt * 16 + (lane >> 4) * 4;
#pragma unroll
            for (int r = 0; r < 4; ++r)
#pragma unroll
                for (int j = 0; j < KK; ++j) pbuf[rowbase + r][wn * 6 + j] = p[r][j];
        }
    }
    __syncthreads();
    if (tid < 64) {
        int node = blkBase + tid;
        if (node < NN) {
            float a[KK], an2 = 0.f;
#pragma unroll
            for (int j = 0; j < KK; ++j) {
                a[j] = pbuf[tid][j] + pbuf[tid][6 + j] + b2[j];
                an2 = fmaf(a[j], a[j], an2);
            }
            float an = sqrtf(an2);
            bool valid = (an2 > 0.f) && isfinite(an);
            float g5[KK], ssum = 0.f;
#pragma unroll
            for (int j = 0; j < KK; ++j) {
                g5[j] = valid ? (a[j] / an) : RSQRT5;
                gout[j * NN + node] = g5[j];
                ssum += g5[j];
            }
            // fused walk step 1: state uniform INIT_VAL -> d = INIT * sum(g)
            float d = ssum * INIT_VAL;
#pragma unroll
            for (int j = 0; j < KK; ++j)
                atomicAdd(&sA[j * NN + nbrT[j * NN + node]], g5[j] * d);
        }
    }
}

// ---------------- walk step: s_p = g (g.u); scatter-add ----------------
__global__ void walk_step_kernel(const float* __restrict__ g, const int* __restrict__ nbrT,
                                 const float* __restrict__ u, float* __restrict__ v) {
    int i = blockIdx.x * blockDim.x + threadIdx.x;
    if (i >= NN) return;
    float gj[KK], d = 0.f;
#pragma unroll
    for (int j = 0; j < KK; ++j) {
        gj[j] = g[j * NN + i];
        d = fmaf(gj[j], u[j * NN + i], d);
    }
#pragma unroll
    for (int j = 0; j < KK; ++j)
        atomicAdd(&v[j * NN + nbrT[j * NN + i]], gj[j] * d);
}

// ---------------- global sum of squares (float4) ----------------
__global__ void norm_reduce_kernel(const float* __restrict__ u, float* __restrict__ ss) {
    int i = blockIdx.x * blockDim.x + threadIdx.x;
    const int total4 = (KK * NN) / 4;  // 125000
    float s = 0.f;
    for (int idx = i; idx < total4; idx += gridDim.x * blockDim.x) {
        float4 x = reinterpret_cast<const float4*>(u)[idx];
        s = fmaf(x.x, x.x, s);
        s = fmaf(x.y, x.y, s);
        s = fmaf(x.z, x.z, s);
        s = fmaf(x.w, x.w, s);
    }
#pragma unroll
    for (int off = 32; off > 0; off >>= 1) s += __shfl_xor(s, off, 64);
    if ((threadIdx.x & 63) == 0) atomicAdd(ss, s);
}

// ---------------- out[i] = sum_j |u[j][i]| / ||u|| ----------------
__global__ void finalize_kernel(const float* __restrict__ u, const float* __restrict__ ss,
                                float* __restrict__ out) {
    int i = blockIdx.x * blockDim.x + threadIdx.x;
    if (i >= NN) return;
    float s = 0.f;
#pragma unroll
    for (int j = 0; j < KK; ++j) s += fabsf(u[j * NN + i]);
    float nrm = sqrtf(*ss);
    out[i] = (nrm > 0.f) ? (s / nrm) : (KK * INIT_VAL);
}

extern "C" void kernel_launch(void* const* d_in, const int* in_sizes, int n_in,
                              void* d_out, int out_size, void* d_ws, size_t ws_size,
                              hipStream_t stream) {
    const float* emb = (const float*)d_in[0];
    const float* qv  = (const float*)d_in[1];
    const float* W1  = (const float*)d_in[2];
    const float* b1  = (const float*)d_in[3];
    const float* W2  = (const float*)d_in[4];
    const float* b2  = (const float*)d_in[5];
    const int*   nbr = (const int*)d_in[6];
    float* out = (float*)d_out;

    char* ws = (char*)d_ws;
    size_t off = 0;
    auto alloc = [&](size_t bytes) {
        char* p = ws + off;
        off += (bytes + 255) & ~(size_t)255;
        return p;
    };
    float*  b1p  = (float*)alloc(HH * sizeof(float));
    ushort* W1h  = (ushort*)alloc((size_t)DD * HH * sizeof(ushort));
    float*  gbuf = (float*)alloc((size_t)KK * NN * sizeof(float));
    int*    nbrT = (int*)  alloc((size_t)KK * NN * sizeof(int));
    float*  sA   = (float*)alloc((size_t)KK * NN * sizeof(float));
    float*  sB   = (float*)alloc((size_t)KK * NN * sizeof(float));
    float*  sC   = (float*)alloc((size_t)KK * NN * sizeof(float));
    float*  ssp  = (float*)alloc(sizeof(float));

    const int nblk = (NN + 255) / 256;   // 391

    prep_kernel<<<25 + nblk, 256, 0, stream>>>(qv, W1, b1, nbr, b1p, W1h,
                                               nbrT, sA, sB, sC, ssp);
    // mlp computes g AND performs walk step 1 (scatter into sA)
    mlp_mfma_kernel<<<(NN + 63) / 64, 256, 0, stream>>>(emb, W1h, b1p, W2, b2,
                                                        nbrT, gbuf, sA);

    walk_step_kernel<<<nblk, 256, 0, stream>>>(gbuf, nbrT, sA, sB);
    walk_step_kernel<<<nblk, 256, 0, stream>>>(gbuf, nbrT, sB, sC);

    norm_reduce_kernel<<<512, 256, 0, stream>>>(sC, ssp);
    finalize_kernel<<<nblk, 256, 0, stream>>>(sC, ssp, out);
}

// Round 13
// 147.790 us; speedup vs baseline: 1.4851x; 1.0564x over previous
//
#include <hip/hip_runtime.h>
#include <hip/hip_bf16.h>
#include <math.h>

#define NN 100000
#define DD 384
#define HH 128
#define KK 5

typedef __attribute__((ext_vector_type(8))) short short8;
typedef __attribute__((ext_vector_type(4))) float f32x4;

constexpr float INIT_VAL = 1.4142135623730951e-3f; // 1/sqrt(N*K)
constexpr float RSQRT5   = 0.44721359549995793f;   // 1/sqrt(5)

// f32 -> bf16 round-to-nearest-even
__device__ __forceinline__ ushort bf16rn(float x) {
    unsigned u = __float_as_uint(x);
    return (ushort)((u + 0x7FFFu + ((u >> 16) & 1u)) >> 16);
}

// ---------------- fused prep ----------------
__global__ __launch_bounds__(256) void prep_kernel(
    const float* __restrict__ qv, const float* __restrict__ W1,
    const float* __restrict__ b1, const int* __restrict__ nbr,
    float* __restrict__ b1p, ushort* __restrict__ W1h,
    int* __restrict__ nbrT, float* __restrict__ sA, float* __restrict__ sB,
    float* __restrict__ sC, float* __restrict__ ssp) {
    const int b = blockIdx.x, tid = threadIdx.x;
    if (b == 0) {
        __shared__ float part[256];
        const int h = tid & 127, half = tid >> 7;
        float s = 0.f;
        const float* Wq = W1 + (size_t)(DD + half * 192) * HH + h;
        const float* qh = qv + half * 192;
#pragma unroll 8
        for (int k = 0; k < 192; ++k)
            s = fmaf(qh[k], Wq[(size_t)k * HH], s);
        part[tid] = s;
        __syncthreads();
        if (tid < HH) b1p[tid] = part[tid] + part[tid + 128] + b1[tid];
        if (tid == 0) ssp[0] = 0.f;
    } else if (b <= 24) {
        int t = (b - 1) * 256 + tid;       // t = (c*12 + ks)*64 + lane, t < 6144
        int l = t & 63;
        int ks = (t >> 6) % 12;
        int c = (t >> 6) / 12;             // hidden 16-col block 0..7
        int k0 = ks * 32 + ((l >> 4) << 3);
        int col = c * 16 + (l & 15);
#pragma unroll
        for (int e = 0; e < 8; ++e)
            W1h[(size_t)t * 8 + e] = bf16rn(W1[(size_t)(k0 + e) * HH + col]);
    } else {
        int i = (b - 25) * 256 + tid;
        if (i < NN) {
#pragma unroll
            for (int j = 0; j < KK; ++j) {
                nbrT[j * NN + i] = nbr[i * KK + j];
                sA[j * NN + i] = 0.f;
                sB[j * NN + i] = 0.f;
                sC[j * NN + i] = 0.f;
            }
        }
    }
}

// ---------------- single-bf16 MFMA MLP, 32-node tiles / max TLP + fused walk1 ----------------
// 3125 blocks x 32 nodes. 4 waves; wave w computes ALL 32 rows x its 32-col quarter.
// A staged f32->bf16(RNE) in 8 KB LDS (XOR swizzle); B pre-packed bf16 frags from L2.
__global__ __launch_bounds__(256) void mlp_mfma_kernel(
    const float* __restrict__ emb, const ushort* __restrict__ W1h,
    const float* __restrict__ b1p, const float* __restrict__ W2,
    const float* __restrict__ b2, const int* __restrict__ nbrT,
    float* __restrict__ gout /* [KK][NN] */, float* __restrict__ sA) {
    __shared__ __align__(16) ushort Ah[32 * 128];  // 8 KB
    __shared__ float pbuf[32][21];                 // 4 waves x 5 + pad

    const int tid = threadIdx.x;
    const int lane = tid & 63;
    const int wn = tid >> 6;   // col quarter 0..3
    const int blkBase = blockIdx.x * 32;

    f32x4 acc[2][2];
#pragma unroll
    for (int mt = 0; mt < 2; ++mt)
#pragma unroll
        for (int nt = 0; nt < 2; ++nt) acc[mt][nt] = (f32x4){0.f, 0.f, 0.f, 0.f};

    float4 aregs[4];
    auto issueA = [&](int t) {
#pragma unroll
        for (int i = 0; i < 4; ++i) {
            int idx = tid + i * 256;        // 0..1023
            int r = idx >> 5, c = idx & 31;
            int node = min(blkBase + r, NN - 1);
            aregs[i] = *reinterpret_cast<const float4*>(&emb[(size_t)node * DD + t * 128 + c * 4]);
        }
    };
    auto writeLDS = [&]() {
#pragma unroll
        for (int i = 0; i < 4; ++i) {
            int idx = tid + i * 256;
            int r = idx >> 5, c = idx & 31;
            ushort4 hv;
            hv.x = bf16rn(aregs[i].x);
            hv.y = bf16rn(aregs[i].y);
            hv.z = bf16rn(aregs[i].z);
            hv.w = bf16rn(aregs[i].w);
            int byte = (r * 256 + c * 8) ^ ((r & 7) << 4);
            *reinterpret_cast<ushort4*>(reinterpret_cast<char*>(Ah) + byte) = hv;
        }
    };

    issueA(0);
    writeLDS();
    __syncthreads();

#pragma unroll
    for (int t = 0; t < 3; ++t) {
        if (t < 2) issueA(t + 1);  // in flight across the whole compute phase

        short8 bh[2][2], ah[2][2];
        auto loadB = [&](int kt, int s) {
            int ks = t * 4 + kt;
#pragma unroll
            for (int nt = 0; nt < 2; ++nt) {
                int c = wn * 2 + nt;
                size_t off = ((size_t)(c * 12 + ks) * 64 + lane) * 8;
                bh[s][nt] = *reinterpret_cast<const short8*>(&W1h[off]);
            }
        };
        auto loadA = [&](int kt, int s) {
#pragma unroll
            for (int mt = 0; mt < 2; ++mt) {
                int row = mt * 16 + (lane & 15);
                int byte = (row * 256 + kt * 64 + ((lane >> 4) << 4)) ^ ((row & 7) << 4);
                ah[s][mt] = *reinterpret_cast<const short8*>(reinterpret_cast<const char*>(Ah) + byte);
            }
        };

        loadB(0, 0);
        loadA(0, 0);
#pragma unroll
        for (int kt = 0; kt < 4; ++kt) {
            const int cur = kt & 1, nxt = cur ^ 1;
            if (kt < 3) {
                loadB(kt + 1, nxt);
                loadA(kt + 1, nxt);
            }
#pragma unroll
            for (int mt = 0; mt < 2; ++mt)
#pragma unroll
                for (int nt = 0; nt < 2; ++nt)
                    acc[mt][nt] = __builtin_amdgcn_mfma_f32_16x16x32_bf16(ah[cur][mt], bh[cur][nt], acc[mt][nt], 0, 0, 0);
        }

        if (t < 2) {
            __syncthreads();   // all waves done reading tile t
            writeLDS();        // load wait lands here, hidden by compute above
            __syncthreads();
        }
    }

    // epilogue: v = relu(h + b1p); p[j] = sum over this wave's 32 cols of v*W2
    float b1v[2], w2v[2][KK];
#pragma unroll
    for (int nt = 0; nt < 2; ++nt) {
        int h = (wn * 2 + nt) * 16 + (lane & 15);
        b1v[nt] = b1p[h];
#pragma unroll
        for (int j = 0; j < KK; ++j) w2v[nt][j] = W2[h * KK + j];
    }
#pragma unroll
    for (int mt = 0; mt < 2; ++mt) {
        float p[4][KK];
#pragma unroll
        for (int r = 0; r < 4; ++r)
#pragma unroll
            for (int j = 0; j < KK; ++j) p[r][j] = 0.f;
#pragma unroll
        for (int nt = 0; nt < 2; ++nt)
#pragma unroll
            for (int r = 0; r < 4; ++r) {
                float v = fmaxf(acc[mt][nt][r] + b1v[nt], 0.f);
#pragma unroll
                for (int j = 0; j < KK; ++j) p[r][j] = fmaf(v, w2v[nt][j], p[r][j]);
            }
#pragma unroll
        for (int off = 1; off < 16; off <<= 1)
#pragma unroll
            for (int r = 0; r < 4; ++r)
#pragma unroll
                for (int j = 0; j < KK; ++j) p[r][j] += __shfl_xor(p[r][j], off, 64);
        if ((lane & 15) == 0) {
            int rowbase = mt * 16 + (lane >> 4) * 4;
#pragma unroll
            for (int r = 0; r < 4; ++r)
#pragma unroll
                for (int j = 0; j < KK; ++j) pbuf[rowbase + r][wn * 5 + j] = p[r][j];
        }
    }
    __syncthreads();
    if (tid < 32) {
        int node = blkBase + tid;
        if (node < NN) {
            float a[KK], an2 = 0.f;
#pragma unroll
            for (int j = 0; j < KK; ++j) {
                a[j] = pbuf[tid][j] + pbuf[tid][5 + j] + pbuf[tid][10 + j] +
                       pbuf[tid][15 + j] + b2[j];
                an2 = fmaf(a[j], a[j], an2);
            }
            float an = sqrtf(an2);
            bool valid = (an2 > 0.f) && isfinite(an);
            float g5[KK], ssum = 0.f;
#pragma unroll
            for (int j = 0; j < KK; ++j) {
                g5[j] = valid ? (a[j] / an) : RSQRT5;
                gout[j * NN + node] = g5[j];
                ssum += g5[j];
            }
            // fused walk step 1: state uniform INIT_VAL -> d = INIT * sum(g)
            float d = ssum * INIT_VAL;
#pragma unroll
            for (int j = 0; j < KK; ++j)
                atomicAdd(&sA[j * NN + nbrT[j * NN + node]], g5[j] * d);
        }
    }
}

// ---------------- walk step: s_p = g (g.u); scatter-add ----------------
__global__ void walk_step_kernel(const float* __restrict__ g, const int* __restrict__ nbrT,
                                 const float* __restrict__ u, float* __restrict__ v) {
    int i = blockIdx.x * blockDim.x + threadIdx.x;
    if (i >= NN) return;
    float gj[KK], d = 0.f;
#pragma unroll
    for (int j = 0; j < KK; ++j) {
        gj[j] = g[j * NN + i];
        d = fmaf(gj[j], u[j * NN + i], d);
    }
#pragma unroll
    for (int j = 0; j < KK; ++j)
        atomicAdd(&v[j * NN + nbrT[j * NN + i]], gj[j] * d);
}

// ---------------- global sum of squares (float4) ----------------
__global__ void norm_reduce_kernel(const float* __restrict__ u, float* __restrict__ ss) {
    int i = blockIdx.x * blockDim.x + threadIdx.x;
    const int total4 = (KK * NN) / 4;  // 125000
    float s = 0.f;
    for (int idx = i; idx < total4; idx += gridDim.x * blockDim.x) {
        float4 x = reinterpret_cast<const float4*>(u)[idx];
        s = fmaf(x.x, x.x, s);
        s = fmaf(x.y, x.y, s);
        s = fmaf(x.z, x.z, s);
        s = fmaf(x.w, x.w, s);
    }
#pragma unroll
    for (int off = 32; off > 0; off >>= 1) s += __shfl_xor(s, off, 64);
    if ((threadIdx.x & 63) == 0) atomicAdd(ss, s);
}

// ---------------- out[i] = sum_j |u[j][i]| / ||u|| ----------------
__global__ void finalize_kernel(const float* __restrict__ u, const float* __restrict__ ss,
                                float* __restrict__ out) {
    int i = blockIdx.x * blockDim.x + threadIdx.x;
    if (i >= NN) return;
    float s = 0.f;
#pragma unroll
    for (int j = 0; j < KK; ++j) s += fabsf(u[j * NN + i]);
    float nrm = sqrtf(*ss);
    out[i] = (nrm > 0.f) ? (s / nrm) : (KK * INIT_VAL);
}

extern "C" void kernel_launch(void* const* d_in, const int* in_sizes, int n_in,
                              void* d_out, int out_size, void* d_ws, size_t ws_size,
                              hipStream_t stream) {
    const float* emb = (const float*)d_in[0];
    const float* qv  = (const float*)d_in[1];
    const float* W1  = (const float*)d_in[2];
    const float* b1  = (const float*)d_in[3];
    const float* W2  = (const float*)d_in[4];
    const float* b2  = (const float*)d_in[5];
    const int*   nbr = (const int*)d_in[6];
    float* out = (float*)d_out;

    char* ws = (char*)d_ws;
    size_t off = 0;
    auto alloc = [&](size_t bytes) {
        char* p = ws + off;
        off += (bytes + 255) & ~(size_t)255;
        return p;
    };
    float*  b1p  = (float*)alloc(HH * sizeof(float));
    ushort* W1h  = (ushort*)alloc((size_t)DD * HH * sizeof(ushort));
    float*  gbuf = (float*)alloc((size_t)KK * NN * sizeof(float));
    int*    nbrT = (int*)  alloc((size_t)KK * NN * sizeof(int));
    float*  sA   = (float*)alloc((size_t)KK * NN * sizeof(float));
    float*  sB   = (float*)alloc((size_t)KK * NN * sizeof(float));
    float*  sC   = (float*)alloc((size_t)KK * NN * sizeof(float));
    float*  ssp  = (float*)alloc(sizeof(float));

    const int nblk = (NN + 255) / 256;   // 391

    prep_kernel<<<25 + nblk, 256, 0, stream>>>(qv, W1, b1, nbr, b1p, W1h,
                                               nbrT, sA, sB, sC, ssp);
    // 3125 blocks x 32 nodes; mlp computes g AND performs walk step 1
    mlp_mfma_kernel<<<(NN + 31) / 32, 256, 0, stream>>>(emb, W1h, b1p, W2, b2,
                                                        nbrT, gbuf, sA);

    walk_step_kernel<<<nblk, 256, 0, stream>>>(gbuf, nbrT, sA, sB);
    walk_step_kernel<<<nblk, 256, 0, stream>>>(gbuf, nbrT, sB, sC);

    norm_reduce_kernel<<<512, 256, 0, stream>>>(sC, ssp);
    finalize_kernel<<<nblk, 256, 0, stream>>>(sC, ssp, out);
}